// Round 1
// baseline (1951.235 us; speedup 1.0000x reference)
//
#include <hip/hip_runtime.h>
#include <cstddef>
#include <cstdint>

#define LRELU_ALPHA 0.2f

// ---------------------------------------------------------------------------
// CSR build: count -> exclusive scan -> scatter
// ---------------------------------------------------------------------------
__global__ __launch_bounds__(256) void count_kernel(const int* __restrict__ src,
                                                    int* __restrict__ cnt, int E)
{
    int i = blockIdx.x * blockDim.x + threadIdx.x;
    int stride = gridDim.x * blockDim.x;
    for (; i < E; i += stride) atomicAdd(&cnt[src[i]], 1);
}

__global__ __launch_bounds__(1024) void scan_kernel(const int* __restrict__ cnt,
                                                    int* __restrict__ rowptr,
                                                    int* __restrict__ cursor, int n)
{
    __shared__ int buf[1024];
    __shared__ int s_carry;
    if (threadIdx.x == 0) s_carry = 0;
    __syncthreads();
    for (int base = 0; base < n; base += 1024) {
        int i = base + (int)threadIdx.x;
        int v = (i < n) ? cnt[i] : 0;
        buf[threadIdx.x] = v;
        __syncthreads();
        for (int off = 1; off < 1024; off <<= 1) {
            int t = (threadIdx.x >= (unsigned)off) ? buf[threadIdx.x - off] : 0;
            __syncthreads();
            buf[threadIdx.x] += t;
            __syncthreads();
        }
        int carry = s_carry;
        int excl = carry + buf[threadIdx.x] - v;
        if (i < n) { rowptr[i] = excl; cursor[i] = excl; }
        int total = buf[1023];
        __syncthreads();
        if (threadIdx.x == 0) s_carry = carry + total;
        __syncthreads();
    }
    if (threadIdx.x == 0) rowptr[n] = s_carry;
}

__global__ __launch_bounds__(256) void scatter_kernel(const int* __restrict__ src,
                                                      const int* __restrict__ dst,
                                                      int* __restrict__ cursor,
                                                      int* __restrict__ csr_dst, int E)
{
    int i = blockIdx.x * blockDim.x + threadIdx.x;
    int stride = gridDim.x * blockDim.x;
    for (; i < E; i += stride) {
        int s = src[i];
        int p = atomicAdd(&cursor[s], 1);
        csr_dst[p] = dst[i];
    }
}

// ---------------------------------------------------------------------------
// fp32 tiled GEMM: C[M,N] = A[M,K] @ W[K,N].  64x64 tile, 256 thr, 4x4/thread
// ---------------------------------------------------------------------------
#define KC 16
__global__ __launch_bounds__(256) void gemm_kernel(const float* __restrict__ A,
                                                   const float* __restrict__ W,
                                                   float* __restrict__ C,
                                                   int M, int N, int K)
{
    __shared__ __align__(16) float As[KC][64];   // [k][m]
    __shared__ __align__(16) float Ws[KC][64];   // [k][n]
    const int tid = threadIdx.x;
    const int tx = tid & 15;        // n quad
    const int ty = tid >> 4;        // m quad
    const int m0 = blockIdx.x * 64;
    const int n0 = blockIdx.y * 64;
    float acc[4][4] = {};
    for (int k0 = 0; k0 < K; k0 += KC) {
#pragma unroll
        for (int t = 0; t < 4; ++t) {           // A chunk 64x16 -> As[k][m]
            int idx = tid + t * 256;
            int m = idx >> 4, k = idx & 15;
            int gm = m0 + m;
            As[k][m] = (gm < M) ? A[(size_t)gm * K + (k0 + k)] : 0.f;
        }
#pragma unroll
        for (int t = 0; t < 4; ++t) {           // W chunk 16x64 -> Ws[k][n]
            int idx = tid + t * 256;
            int k = idx >> 6, n = idx & 63;
            Ws[k][n] = W[(size_t)(k0 + k) * N + (n0 + n)];
        }
        __syncthreads();
#pragma unroll
        for (int k = 0; k < KC; ++k) {
            float4 a4 = *(const float4*)&As[k][ty * 4];
            float4 b4 = *(const float4*)&Ws[k][tx * 4];
            acc[0][0] += a4.x * b4.x; acc[0][1] += a4.x * b4.y;
            acc[0][2] += a4.x * b4.z; acc[0][3] += a4.x * b4.w;
            acc[1][0] += a4.y * b4.x; acc[1][1] += a4.y * b4.y;
            acc[1][2] += a4.y * b4.z; acc[1][3] += a4.y * b4.w;
            acc[2][0] += a4.z * b4.x; acc[2][1] += a4.z * b4.y;
            acc[2][2] += a4.z * b4.z; acc[2][3] += a4.z * b4.w;
            acc[3][0] += a4.w * b4.x; acc[3][1] += a4.w * b4.y;
            acc[3][2] += a4.w * b4.z; acc[3][3] += a4.w * b4.w;
        }
        __syncthreads();
    }
#pragma unroll
    for (int i = 0; i < 4; ++i) {
        int gm = m0 + ty * 4 + i;
        if (gm < M) {
            float4 v = make_float4(acc[i][0], acc[i][1], acc[i][2], acc[i][3]);
            *(float4*)&C[(size_t)gm * N + n0 + tx * 4] = v;
        }
    }
}

// ---------------------------------------------------------------------------
// per-row s_src/s_dst: s_src[i] = h[i,:] . a[0:D], s_dst[i] = h[i,:] . a[D:2D]
// one wave per row
// ---------------------------------------------------------------------------
template <int D>
__global__ __launch_bounds__(256) void s_kernel(const float* __restrict__ h,
                                                const float* __restrict__ a,
                                                float* __restrict__ ssrc,
                                                float* __restrict__ sdst, int nrows)
{
    constexpr int VPT = D / 64;
    int lane = threadIdx.x & 63;
    int row = blockIdx.x * 4 + (threadIdx.x >> 6);
    if (row >= nrows) return;
    const float* hp = h + (size_t)row * D + lane * VPT;
    float ps = 0.f, pd = 0.f;
    if constexpr (VPT == 4) {
        float4 v = *(const float4*)hp;
        float4 as = *(const float4*)&a[lane * 4];
        float4 ad = *(const float4*)&a[D + lane * 4];
        ps = v.x * as.x + v.y * as.y + v.z * as.z + v.w * as.w;
        pd = v.x * ad.x + v.y * ad.y + v.z * ad.z + v.w * ad.w;
    } else {
        float2 v = *(const float2*)hp;
        float2 as = *(const float2*)&a[lane * 2];
        float2 ad = *(const float2*)&a[D + lane * 2];
        ps = v.x * as.x + v.y * as.y;
        pd = v.x * ad.x + v.y * ad.y;
    }
#pragma unroll
    for (int off = 32; off; off >>= 1) {
        ps += __shfl_xor(ps, off);
        pd += __shfl_xor(pd, off);
    }
    if (lane == 0) { ssrc[row] = ps; sdst[row] = pd; }
}

// ---------------------------------------------------------------------------
// per-row edge softmax (leaky_relu -> max -> exp -> sum -> normalize)
// one wave per row; attn[] indexed in CSR order
// ---------------------------------------------------------------------------
__global__ __launch_bounds__(256) void attn_kernel(const float* __restrict__ ssrc,
                                                   const float* __restrict__ sdst,
                                                   const int* __restrict__ csr_dst,
                                                   const int* __restrict__ rowptr,
                                                   float* __restrict__ attn, int nrows)
{
    int lane = threadIdx.x & 63;
    int row = blockIdx.x * 4 + (threadIdx.x >> 6);
    if (row >= nrows) return;
    int beg = rowptr[row], end = rowptr[row + 1];
    if (beg == end) return;
    float ss = ssrc[row];
    float m = -INFINITY;
    for (int e = beg + lane; e < end; e += 64) {
        float sc = ss + sdst[csr_dst[e]];
        sc = (sc > 0.f) ? sc : LRELU_ALPHA * sc;
        attn[e] = sc;
        m = fmaxf(m, sc);
    }
#pragma unroll
    for (int off = 32; off; off >>= 1) m = fmaxf(m, __shfl_xor(m, off));
    float z = 0.f;
    for (int e = beg + lane; e < end; e += 64) {
        float ex = expf(attn[e] - m);
        attn[e] = ex;
        z += ex;
    }
#pragma unroll
    for (int off = 32; off; off >>= 1) z += __shfl_xor(z, off);
    float rz = 1.f / z;
    for (int e = beg + lane; e < end; e += 64) attn[e] *= rz;
}

// ---------------------------------------------------------------------------
// per-row aggregation: out[i,:] = elu( sum_e attn_e * h[dst_e,:] )
// one wave per row, each lane owns D/64 columns
// ---------------------------------------------------------------------------
__device__ __forceinline__ float eluf(float x) { return x > 0.f ? x : expm1f(x); }

template <int D>
__global__ __launch_bounds__(256) void aggregate_kernel(const float* __restrict__ h,
                                                        const float* __restrict__ attn,
                                                        const int* __restrict__ csr_dst,
                                                        const int* __restrict__ rowptr,
                                                        float* __restrict__ out, int nrows)
{
    constexpr int VPT = D / 64;
    int lane = threadIdx.x & 63;
    int row = blockIdx.x * 4 + (threadIdx.x >> 6);
    if (row >= nrows) return;
    int beg = rowptr[row], end = rowptr[row + 1];
    float acc[VPT] = {};
    for (int e = beg; e < end; ++e) {
        float a = attn[e];
        int d = csr_dst[e];
        const float* hp = h + (size_t)d * D + lane * VPT;
        if constexpr (VPT == 4) {
            float4 v = *(const float4*)hp;
            acc[0] += a * v.x; acc[1] += a * v.y;
            acc[2] += a * v.z; acc[3] += a * v.w;
        } else {
            float2 v = *(const float2*)hp;
            acc[0] += a * v.x; acc[1] += a * v.y;
        }
    }
    float* op = out + (size_t)row * D + lane * VPT;
    if constexpr (VPT == 4) {
        float4 o = make_float4(eluf(acc[0]), eluf(acc[1]), eluf(acc[2]), eluf(acc[3]));
        *(float4*)op = o;
    } else {
        float2 o = make_float2(eluf(acc[0]), eluf(acc[1]));
        *(float2*)op = o;
    }
}

// ---------------------------------------------------------------------------
// final: logits = h1 @ lin_w + lin_b ; out = log_softmax(logits)
// one wave per row (lanes 0..39 hold one logit each)
// ---------------------------------------------------------------------------
__global__ __launch_bounds__(256) void final_kernel(const float* __restrict__ h, // [N,128]
                                                    const float* __restrict__ lw, // [128,40]
                                                    const float* __restrict__ lb, // [40]
                                                    float* __restrict__ out, int nrows)
{
    __shared__ __align__(16) float rowbuf[4][128];
    int lane = threadIdx.x & 63;
    int wv = threadIdx.x >> 6;
    int row = blockIdx.x * 4 + wv;
    bool active = row < nrows;
    if (active) {
        float2 v = *(const float2*)&h[(size_t)row * 128 + lane * 2];
        rowbuf[wv][lane * 2] = v.x;
        rowbuf[wv][lane * 2 + 1] = v.y;
    }
    __syncthreads();
    float logit = 0.f;
    if (active && lane < 40) {
        float s = lb[lane];
        for (int k = 0; k < 128; ++k) s += rowbuf[wv][k] * lw[k * 40 + lane];
        logit = s;
    }
    float v = (active && lane < 40) ? logit : -INFINITY;
#pragma unroll
    for (int off = 32; off; off >>= 1) v = fmaxf(v, __shfl_xor(v, off));
    float ex = (active && lane < 40) ? expf(logit - v) : 0.f;
    float zs = ex;
#pragma unroll
    for (int off = 32; off; off >>= 1) zs += __shfl_xor(zs, off);
    if (active && lane < 40) out[(size_t)row * 40 + lane] = logit - v - logf(zs);
}

// ---------------------------------------------------------------------------
extern "C" void kernel_launch(void* const* d_in, const int* in_sizes, int n_in,
                              void* d_out, int out_size, void* d_ws, size_t ws_size,
                              hipStream_t stream)
{
    const float* x   = (const float*)d_in[0];   // [N,256]
    const int*  edge = (const int*)d_in[1];     // [2,E]
    const float* W0  = (const float*)d_in[2];   // [256,256]
    const float* a0  = (const float*)d_in[3];   // [512,1]
    const float* W1  = (const float*)d_in[4];   // [256,128]
    const float* a1  = (const float*)d_in[5];   // [256,1]
    const float* lw  = (const float*)d_in[6];   // [128,40]
    const float* lb  = (const float*)d_in[7];   // [40]
    float* out = (float*)d_out;

    const int N = in_sizes[0] / 256;
    const int E = in_sizes[1] / 2;
    const int* src = edge;
    const int* dst = edge + E;

    // workspace layout (floats)
    float* hA   = (float*)d_ws;                 // N*256   (h of current layer)
    float* hB   = hA + (size_t)N * 256;         // N*256   (aggregated output)
    float* ssrc = hB + (size_t)N * 256;         // N
    float* sdst = ssrc + N;                     // N
    float* attn = sdst + N;                     // E
    int* rowptr  = (int*)(attn + E);            // N+1
    int* cursor  = rowptr + (N + 1);            // N
    int* cnt     = cursor + N;                  // N
    int* csr_dst = cnt + N;                     // E

    const int rowBlocks = (N + 3) / 4;

    // ---- CSR build (edges fixed per call; reused by both layers) ----
    hipMemsetAsync(cnt, 0, (size_t)N * sizeof(int), stream);
    count_kernel<<<2048, 256, 0, stream>>>(src, cnt, E);
    scan_kernel<<<1, 1024, 0, stream>>>(cnt, rowptr, cursor, N);
    scatter_kernel<<<2048, 256, 0, stream>>>(src, dst, cursor, csr_dst, E);

    // ---- layer 0: d = 256 ----
    gemm_kernel<<<dim3((N + 63) / 64, 4), 256, 0, stream>>>(x, W0, hA, N, 256, 256);
    s_kernel<256><<<rowBlocks, 256, 0, stream>>>(hA, a0, ssrc, sdst, N);
    attn_kernel<<<rowBlocks, 256, 0, stream>>>(ssrc, sdst, csr_dst, rowptr, attn, N);
    aggregate_kernel<256><<<rowBlocks, 256, 0, stream>>>(hA, attn, csr_dst, rowptr, hB, N);

    // ---- layer 1: d = 128 ----
    gemm_kernel<<<dim3((N + 63) / 64, 2), 256, 0, stream>>>(hB, W1, hA, N, 128, 256);
    s_kernel<128><<<rowBlocks, 256, 0, stream>>>(hA, a1, ssrc, sdst, N);
    attn_kernel<<<rowBlocks, 256, 0, stream>>>(ssrc, sdst, csr_dst, rowptr, attn, N);
    aggregate_kernel<128><<<rowBlocks, 256, 0, stream>>>(hA, attn, csr_dst, rowptr, hB, N);

    // ---- final linear + log_softmax ----
    final_kernel<<<rowBlocks, 256, 0, stream>>>(hB, lw, lb, out, N);
}

// Round 2
// 1120.232 us; speedup vs baseline: 1.7418x; 1.7418x over previous
//
#include <hip/hip_runtime.h>
#include <cstddef>
#include <cstdint>

#define LRELU_ALPHA 0.2f

typedef _Float16 f16x8 __attribute__((ext_vector_type(8)));
typedef _Float16 f16x4 __attribute__((ext_vector_type(4)));
typedef _Float16 f16x2 __attribute__((ext_vector_type(2)));
typedef float    f32x4 __attribute__((ext_vector_type(4)));

// ---------------------------------------------------------------------------
// CSR build: count -> (parallel scan) -> scatter
// ---------------------------------------------------------------------------
__global__ __launch_bounds__(256) void count_kernel(const int* __restrict__ src,
                                                    int* __restrict__ cnt, int E)
{
    int i = blockIdx.x * blockDim.x + threadIdx.x;
    int stride = gridDim.x * blockDim.x;
    for (; i < E; i += stride) atomicAdd(&cnt[src[i]], 1);
}

// per-1024-row chunk sums
__global__ __launch_bounds__(256) void bsum_kernel(const int* __restrict__ cnt,
                                                   int* __restrict__ bsum, int n)
{
    __shared__ int red[4];
    int b = blockIdx.x, t = threadIdx.x;
    int base = b * 1024;
    int s = 0;
#pragma unroll
    for (int j = 0; j < 4; ++j) {
        int i = base + j * 256 + t;
        s += (i < n) ? cnt[i] : 0;
    }
#pragma unroll
    for (int off = 32; off; off >>= 1) s += __shfl_xor(s, off);
    if ((t & 63) == 0) red[t >> 6] = s;
    __syncthreads();
    if (t == 0) bsum[b] = red[0] + red[1] + red[2] + red[3];
}

// exclusive scan of chunk sums (nb <= 128), writes rowptr[N] = total
__global__ __launch_bounds__(128) void bscan_kernel(int* __restrict__ bsum, int nb,
                                                    int* __restrict__ rowptr, int N)
{
    __shared__ int buf[128];
    int t = threadIdx.x;
    int v = (t < nb) ? bsum[t] : 0;
    buf[t] = v;
    __syncthreads();
    for (int off = 1; off < 128; off <<= 1) {
        int u = (t >= off) ? buf[t - off] : 0;
        __syncthreads();
        buf[t] += u;
        __syncthreads();
    }
    if (t < nb) bsum[t] = buf[t] - v;   // exclusive
    if (t == 127) rowptr[N] = buf[127];
}

__global__ __launch_bounds__(256) void chunkscan_kernel(const int* __restrict__ cnt,
                                                        const int* __restrict__ bsum,
                                                        int* __restrict__ rowptr,
                                                        int* __restrict__ cursor, int n)
{
    __shared__ int tsum[256];
    int b = blockIdx.x, t = threadIdx.x;
    int base = b * 1024 + t * 4;
    int c[4];
    int s = 0;
#pragma unroll
    for (int j = 0; j < 4; ++j) {
        int i = base + j;
        c[j] = (i < n) ? cnt[i] : 0;
        s += c[j];
    }
    tsum[t] = s;
    __syncthreads();
    for (int off = 1; off < 256; off <<= 1) {
        int u = (t >= off) ? tsum[t - off] : 0;
        __syncthreads();
        tsum[t] += u;
        __syncthreads();
    }
    int run = bsum[b] + tsum[t] - s;
#pragma unroll
    for (int j = 0; j < 4; ++j) {
        int i = base + j;
        if (i < n) { rowptr[i] = run; cursor[i] = run; run += c[j]; }
    }
}

__global__ __launch_bounds__(256) void scatter_kernel(const int* __restrict__ src,
                                                      const int* __restrict__ dst,
                                                      int* __restrict__ cursor,
                                                      int* __restrict__ csr_dst, int E)
{
    int i = blockIdx.x * blockDim.x + threadIdx.x;
    int stride = gridDim.x * blockDim.x;
    for (; i < E; i += stride) {
        int s = src[i];
        int p = atomicAdd(&cursor[s], 1);
        csr_dst[p] = dst[i];
    }
}

// ---------------------------------------------------------------------------
// fp32 -> fp16 convert (4 elems/thread)
// ---------------------------------------------------------------------------
__global__ __launch_bounds__(256) void cvt16_kernel(const float* __restrict__ x,
                                                    _Float16* __restrict__ y, size_t n4)
{
    size_t i = (size_t)blockIdx.x * blockDim.x + threadIdx.x;
    size_t stride = (size_t)gridDim.x * blockDim.x;
    for (; i < n4; i += stride) {
        float4 v = ((const float4*)x)[i];
        f16x4 o = { (_Float16)v.x, (_Float16)v.y, (_Float16)v.z, (_Float16)v.w };
        ((f16x4*)y)[i] = o;
    }
}

// Wt[n][k] = (fp16) W[k][n]
__global__ __launch_bounds__(256) void transpose16_kernel(const float* __restrict__ W,
                                                          _Float16* __restrict__ Wt,
                                                          int K, int Nw)
{
    int i = blockIdx.x * 256 + threadIdx.x;
    if (i < K * Nw) {
        int n = i / K, k = i - n * K;
        Wt[i] = (_Float16)W[(size_t)k * Nw + n];
    }
}

// ---------------------------------------------------------------------------
// MFMA f16 GEMM: C16[M,Nw] = A16[M,K] @ Bt16[Nw,K]^T  (fp32 accum, fp16 out)
// 128x64 tile, BK=32, 4 waves (each 32 rows x 64 cols = 2x4 MFMA frags)
// A and B fragments use the SAME per-lane k-map (8 contiguous at 8*(lane>>4)),
// which is correct under any HW k-bijection; C/D layout per guide (m89).
// ---------------------------------------------------------------------------
#define GBM 128
#define GBN 64
#define GBK 32
#define LDP 40   // padded halves per LDS row (80 B, 16B-aligned, conflict-free)

__global__ __launch_bounds__(256) void gemm16_kernel(const _Float16* __restrict__ A,
                                                     const _Float16* __restrict__ Bt,
                                                     _Float16* __restrict__ C,
                                                     int M, int Nw, int K)
{
    __shared__ __align__(16) _Float16 Ash[GBM * LDP];
    __shared__ __align__(16) _Float16 Bsh[GBN * LDP];
    const int tid = threadIdx.x;
    const int lane = tid & 63;
    const int w = tid >> 6;
    const int m0 = blockIdx.x * GBM;
    const int n0 = blockIdx.y * GBN;
    const int l15 = lane & 15;
    const int kq = lane >> 4;
    const int sr = tid >> 2;   // staging row 0..63
    const int sc = tid & 3;    // 16B segment

    f32x4 acc[2][4] = {};

    for (int k0 = 0; k0 < K; k0 += GBK) {
#pragma unroll
        for (int it = 0; it < 2; ++it) {
            int r = sr + it * 64;
            int gm = m0 + r;
            f16x8 v = {};
            if (gm < M) v = *(const f16x8*)(A + (size_t)gm * K + k0 + sc * 8);
            *(f16x8*)&Ash[r * LDP + sc * 8] = v;
        }
        {
            f16x8 v = *(const f16x8*)(Bt + (size_t)(n0 + sr) * K + k0 + sc * 8);
            *(f16x8*)&Bsh[sr * LDP + sc * 8] = v;
        }
        __syncthreads();

        f16x8 af[2], bf[4];
#pragma unroll
        for (int mt = 0; mt < 2; ++mt)
            af[mt] = *(const f16x8*)&Ash[(w * 32 + mt * 16 + l15) * LDP + kq * 8];
#pragma unroll
        for (int nt = 0; nt < 4; ++nt)
            bf[nt] = *(const f16x8*)&Bsh[(nt * 16 + l15) * LDP + kq * 8];
#pragma unroll
        for (int mt = 0; mt < 2; ++mt)
#pragma unroll
            for (int nt = 0; nt < 4; ++nt)
                acc[mt][nt] = __builtin_amdgcn_mfma_f32_16x16x32_f16(af[mt], bf[nt],
                                                                     acc[mt][nt], 0, 0, 0);
        __syncthreads();
    }

#pragma unroll
    for (int mt = 0; mt < 2; ++mt) {
#pragma unroll
        for (int r = 0; r < 4; ++r) {
            int gm = m0 + w * 32 + mt * 16 + kq * 4 + r;
            if (gm < M) {
#pragma unroll
                for (int nt = 0; nt < 4; ++nt)
                    C[(size_t)gm * Nw + n0 + nt * 16 + l15] = (_Float16)acc[mt][nt][r];
            }
        }
    }
}

// ---------------------------------------------------------------------------
// per-row s_src/s_dst from fp16 h (fp32 accum); one wave per row
// ---------------------------------------------------------------------------
template <int D>
__global__ __launch_bounds__(256) void s16_kernel(const _Float16* __restrict__ h,
                                                  const float* __restrict__ a,
                                                  float* __restrict__ ssrc,
                                                  float* __restrict__ sdst, int nrows)
{
    constexpr int VPT = D / 64;
    int lane = threadIdx.x & 63;
    int row = blockIdx.x * 4 + (threadIdx.x >> 6);
    if (row >= nrows) return;
    const _Float16* hp = h + (size_t)row * D + lane * VPT;
    float ps = 0.f, pd = 0.f;
    if constexpr (VPT == 4) {
        f16x4 v = *(const f16x4*)hp;
        float4 as = *(const float4*)&a[lane * 4];
        float4 ad = *(const float4*)&a[D + lane * 4];
        ps = (float)v[0] * as.x + (float)v[1] * as.y + (float)v[2] * as.z + (float)v[3] * as.w;
        pd = (float)v[0] * ad.x + (float)v[1] * ad.y + (float)v[2] * ad.z + (float)v[3] * ad.w;
    } else {
        f16x2 v = *(const f16x2*)hp;
        float2 as = *(const float2*)&a[lane * 2];
        float2 ad = *(const float2*)&a[D + lane * 2];
        ps = (float)v[0] * as.x + (float)v[1] * as.y;
        pd = (float)v[0] * ad.x + (float)v[1] * ad.y;
    }
#pragma unroll
    for (int off = 32; off; off >>= 1) {
        ps += __shfl_xor(ps, off);
        pd += __shfl_xor(pd, off);
    }
    if (lane == 0) { ssrc[row] = ps; sdst[row] = pd; }
}

// ---------------------------------------------------------------------------
// per-row edge softmax; one wave per row, attn in CSR order
// ---------------------------------------------------------------------------
__global__ __launch_bounds__(256) void attn_kernel(const float* __restrict__ ssrc,
                                                   const float* __restrict__ sdst,
                                                   const int* __restrict__ csr_dst,
                                                   const int* __restrict__ rowptr,
                                                   float* __restrict__ attn, int nrows)
{
    int lane = threadIdx.x & 63;
    int row = blockIdx.x * 4 + (threadIdx.x >> 6);
    if (row >= nrows) return;
    int beg = rowptr[row], end = rowptr[row + 1];
    if (beg == end) return;
    float ss = ssrc[row];
    float m = -INFINITY;
    for (int e = beg + lane; e < end; e += 64) {
        float sc = ss + sdst[csr_dst[e]];
        sc = (sc > 0.f) ? sc : LRELU_ALPHA * sc;
        attn[e] = sc;
        m = fmaxf(m, sc);
    }
#pragma unroll
    for (int off = 32; off; off >>= 1) m = fmaxf(m, __shfl_xor(m, off));
    float z = 0.f;
    for (int e = beg + lane; e < end; e += 64) {
        float ex = expf(attn[e] - m);
        attn[e] = ex;
        z += ex;
    }
#pragma unroll
    for (int off = 32; off; off >>= 1) z += __shfl_xor(z, off);
    float rz = 1.f / z;
    for (int e = beg + lane; e < end; e += 64) attn[e] *= rz;
}

// ---------------------------------------------------------------------------
// aggregation from fp16 h: one wave per row, 32 lanes per edge, 2 edges in
// flight; fold halves with shfl_xor(32); fp16 output (elu applied)
// ---------------------------------------------------------------------------
__device__ __forceinline__ float eluf(float x) { return x > 0.f ? x : expm1f(x); }

template <int D>
__global__ __launch_bounds__(256) void aggregate16_kernel(const _Float16* __restrict__ h,
                                                          const float* __restrict__ attn,
                                                          const int* __restrict__ csr_dst,
                                                          const int* __restrict__ rowptr,
                                                          _Float16* __restrict__ out, int nrows)
{
    constexpr int HPL = D / 32;            // halves per lane: 8 (D=256) or 4 (D=128)
    int lane = threadIdx.x & 63;
    int row = blockIdx.x * 4 + (threadIdx.x >> 6);
    if (row >= nrows) return;
    int beg = rowptr[row], end = rowptr[row + 1];
    int sub = lane >> 5;
    int cl = lane & 31;
    float acc[HPL] = {};
    for (int e = beg + sub; e < end; e += 2) {
        float a = attn[e];
        int d = csr_dst[e];
        const _Float16* hp = h + (size_t)d * D + cl * HPL;
        if constexpr (HPL == 8) {
            f16x8 v = *(const f16x8*)hp;
#pragma unroll
            for (int j = 0; j < 8; ++j) acc[j] += a * (float)v[j];
        } else {
            f16x4 v = *(const f16x4*)hp;
#pragma unroll
            for (int j = 0; j < 4; ++j) acc[j] += a * (float)v[j];
        }
    }
#pragma unroll
    for (int j = 0; j < HPL; ++j) acc[j] += __shfl_xor(acc[j], 32);
    if (sub == 0) {
        _Float16* op = out + (size_t)row * D + cl * HPL;
        if constexpr (HPL == 8) {
            f16x8 o;
#pragma unroll
            for (int j = 0; j < 8; ++j) o[j] = (_Float16)eluf(acc[j]);
            *(f16x8*)op = o;
        } else {
            f16x4 o;
#pragma unroll
            for (int j = 0; j < 4; ++j) o[j] = (_Float16)eluf(acc[j]);
            *(f16x4*)op = o;
        }
    }
}

// ---------------------------------------------------------------------------
// final: logits = h1 @ lin_w + lin_b ; log_softmax; one wave per row
// ---------------------------------------------------------------------------
__global__ __launch_bounds__(256) void final16_kernel(const _Float16* __restrict__ h, // [N,128]
                                                      const float* __restrict__ lw,   // [128,40]
                                                      const float* __restrict__ lb,   // [40]
                                                      float* __restrict__ out, int nrows)
{
    __shared__ __align__(16) float rowbuf[4][128];
    int lane = threadIdx.x & 63;
    int wv = threadIdx.x >> 6;
    int row = blockIdx.x * 4 + wv;
    bool active = row < nrows;
    if (active) {
        f16x2 v = *(const f16x2*)&h[(size_t)row * 128 + lane * 2];
        rowbuf[wv][lane * 2] = (float)v[0];
        rowbuf[wv][lane * 2 + 1] = (float)v[1];
    }
    __syncthreads();
    float logit = 0.f;
    if (active && lane < 40) {
        float s = lb[lane];
        for (int k = 0; k < 128; ++k) s += rowbuf[wv][k] * lw[k * 40 + lane];
        logit = s;
    }
    float v = (active && lane < 40) ? logit : -INFINITY;
#pragma unroll
    for (int off = 32; off; off >>= 1) v = fmaxf(v, __shfl_xor(v, off));
    float ex = (active && lane < 40) ? expf(logit - v) : 0.f;
    float zs = ex;
#pragma unroll
    for (int off = 32; off; off >>= 1) zs += __shfl_xor(zs, off);
    if (active && lane < 40) out[(size_t)row * 40 + lane] = logit - v - logf(zs);
}

// ---------------------------------------------------------------------------
extern "C" void kernel_launch(void* const* d_in, const int* in_sizes, int n_in,
                              void* d_out, int out_size, void* d_ws, size_t ws_size,
                              hipStream_t stream)
{
    const float* x   = (const float*)d_in[0];   // [N,256]
    const int*  edge = (const int*)d_in[1];     // [2,E]
    const float* W0  = (const float*)d_in[2];   // [256,256]
    const float* a0  = (const float*)d_in[3];   // [512,1]
    const float* W1  = (const float*)d_in[4];   // [256,128]
    const float* a1  = (const float*)d_in[5];   // [256,1]
    const float* lw  = (const float*)d_in[6];   // [128,40]
    const float* lb  = (const float*)d_in[7];   // [40]
    float* out = (float*)d_out;

    const int N = in_sizes[0] / 256;
    const int E = in_sizes[1] / 2;
    const int* src = edge;
    const int* dst = edge + E;

    // ---- workspace layout ----
    _Float16* bufA = (_Float16*)d_ws;                 // N*256 halves
    _Float16* bufB = bufA + (size_t)N * 256;          // N*256
    _Float16* bufC = bufB + (size_t)N * 256;          // N*256
    _Float16* W0t  = bufC + (size_t)N * 256;          // 256*256
    _Float16* W1t  = W0t + 256 * 256;                 // 128*256
    float* ssrc = (float*)(W1t + 128 * 256);          // N
    float* sdst = ssrc + N;                            // N
    float* attn = sdst + N;                            // E
    int* rowptr  = (int*)(attn + E);                   // N+1
    int* cursor  = rowptr + (N + 1);                   // N
    int* cnt     = cursor + N;                         // N
    int* csr_dst = cnt + N;                            // E
    int* bsum    = csr_dst + E;                        // <=128

    const int rowBlocks = (N + 3) / 4;
    const int nb = (N + 1023) / 1024;                  // scan chunks (<=128)

    // ---- CSR build ----
    hipMemsetAsync(cnt, 0, (size_t)N * sizeof(int), stream);
    count_kernel<<<2048, 256, 0, stream>>>(src, cnt, E);
    bsum_kernel<<<nb, 256, 0, stream>>>(cnt, bsum, N);
    bscan_kernel<<<1, 128, 0, stream>>>(bsum, nb, rowptr, N);
    chunkscan_kernel<<<nb, 256, 0, stream>>>(cnt, bsum, rowptr, cursor, N);
    scatter_kernel<<<2048, 256, 0, stream>>>(src, dst, cursor, csr_dst, E);

    // ---- fp16 conversions (inputs) ----
    cvt16_kernel<<<2048, 256, 0, stream>>>(x, bufA, (size_t)N * 64);
    transpose16_kernel<<<(256 * 256 + 255) / 256, 256, 0, stream>>>(W0, W0t, 256, 256);
    transpose16_kernel<<<(128 * 256 + 255) / 256, 256, 0, stream>>>(W1, W1t, 256, 128);

    // ---- layer 0: d = 256 ----
    gemm16_kernel<<<dim3((N + GBM - 1) / GBM, 256 / GBN), 256, 0, stream>>>(bufA, W0t, bufB, N, 256, 256);
    s16_kernel<256><<<rowBlocks, 256, 0, stream>>>(bufB, a0, ssrc, sdst, N);
    attn_kernel<<<rowBlocks, 256, 0, stream>>>(ssrc, sdst, csr_dst, rowptr, attn, N);
    aggregate16_kernel<256><<<rowBlocks, 256, 0, stream>>>(bufB, attn, csr_dst, rowptr, bufC, N);

    // ---- layer 1: d = 128 ----
    gemm16_kernel<<<dim3((N + GBM - 1) / GBM, 128 / GBN), 256, 0, stream>>>(bufC, W1t, bufA, N, 128, 256);
    s16_kernel<128><<<rowBlocks, 256, 0, stream>>>(bufA, a1, ssrc, sdst, N);
    attn_kernel<<<rowBlocks, 256, 0, stream>>>(ssrc, sdst, csr_dst, rowptr, attn, N);
    aggregate16_kernel<128><<<rowBlocks, 256, 0, stream>>>(bufA, attn, csr_dst, rowptr, bufB, N);

    // ---- final linear + log_softmax ----
    final16_kernel<<<rowBlocks, 256, 0, stream>>>(bufB, lw, lb, out, N);
}

// Round 3
// 753.369 us; speedup vs baseline: 2.5900x; 1.4870x over previous
//
#include <hip/hip_runtime.h>
#include <cstddef>
#include <cstdint>

#define LRELU_ALPHA 0.2f
#define BIN_SHIFT 9
#define BIN_ROWS  (1 << BIN_SHIFT)   // 512 rows per bucket

typedef _Float16 f16x8 __attribute__((ext_vector_type(8)));
typedef _Float16 f16x4 __attribute__((ext_vector_type(4)));
typedef _Float16 f16x2 __attribute__((ext_vector_type(2)));
typedef float    f32x4 __attribute__((ext_vector_type(4)));

// ---------------------------------------------------------------------------
// CSR build, locality-bucketed:
//   bucket_count -> bucket_scan -> pass1 (bin pairs) -> row_count ->
//   bsum/bscan/chunkscan (rowptr) -> pass2 (scatter within bucket windows)
// ---------------------------------------------------------------------------

// per-block LDS histogram of src>>BIN_SHIFT, flushed with one atomic per bucket
__global__ __launch_bounds__(256) void bucket_count_kernel(const int* __restrict__ src,
                                                           int* __restrict__ bhist, int E)
{
    __shared__ int hist[256];
    int t = threadIdx.x;
    hist[t] = 0;
    __syncthreads();
    int base = blockIdx.x * 4096;
#pragma unroll
    for (int j = 0; j < 16; ++j) {
        int i = base + j * 256 + t;
        if (i < E) atomicAdd(&hist[src[i] >> BIN_SHIFT], 1);
    }
    __syncthreads();
    if (hist[t]) atomicAdd(&bhist[t], hist[t]);
}

// single block: exclusive scan of 256 bucket counts -> bbase[0..256], gcur
__global__ __launch_bounds__(256) void bucket_scan_kernel(const int* __restrict__ bhist,
                                                          int* __restrict__ bbase,
                                                          int* __restrict__ gcur, int E)
{
    __shared__ int buf[256];
    int t = threadIdx.x;
    int v = bhist[t];
    buf[t] = v;
    __syncthreads();
    for (int off = 1; off < 256; off <<= 1) {
        int u = (t >= off) ? buf[t - off] : 0;
        __syncthreads();
        buf[t] += u;
        __syncthreads();
    }
    int excl = buf[t] - v;
    bbase[t] = excl;
    gcur[t] = excl;
    if (t == 255) bbase[256] = buf[255];
}

// bin (src,dst) pairs into bucket-contiguous order; writes are ~128B runs
__global__ __launch_bounds__(256) void pass1_bin_kernel(const int* __restrict__ src,
                                                        const int* __restrict__ dst,
                                                        int* __restrict__ gcur,
                                                        int2* __restrict__ pairs, int E)
{
    __shared__ int hist[256];
    __shared__ int cur[256];
    int t = threadIdx.x;
    hist[t] = 0;
    __syncthreads();
    int base = blockIdx.x * 4096;
    int s_[16], d_[16];
#pragma unroll
    for (int j = 0; j < 16; ++j) {
        int i = base + j * 256 + t;
        if (i < E) {
            s_[j] = src[i];
            d_[j] = dst[i];
            atomicAdd(&hist[s_[j] >> BIN_SHIFT], 1);
        } else s_[j] = -1;
    }
    __syncthreads();
    cur[t] = atomicAdd(&gcur[t], hist[t]);
    __syncthreads();
#pragma unroll
    for (int j = 0; j < 16; ++j) {
        if (s_[j] >= 0) {
            int pos = atomicAdd(&cur[s_[j] >> BIN_SHIFT], 1);
            pairs[pos] = make_int2(s_[j], d_[j]);
        }
    }
}

// one block per bucket: per-row counts via LDS (window = 512 rows)
__global__ __launch_bounds__(256) void row_count_kernel(const int2* __restrict__ pairs,
                                                        const int* __restrict__ bbase,
                                                        int* __restrict__ cnt, int N)
{
    __shared__ int c[BIN_ROWS];
    int b = blockIdx.x, t = threadIdx.x;
    int rowbase = b << BIN_SHIFT;
    int nrows = min(BIN_ROWS, N - rowbase);
    c[t] = 0; c[t + 256] = 0;
    __syncthreads();
    int beg = bbase[b], end = bbase[b + 1];
    for (int i = beg + t; i < end; i += 256)
        atomicAdd(&c[pairs[i].x - rowbase], 1);
    __syncthreads();
    if (t < nrows) cnt[rowbase + t] = c[t];
    if (t + 256 < nrows) cnt[rowbase + t + 256] = c[t + 256];
}

// chunk sums over 1024-row chunks
__global__ __launch_bounds__(256) void bsum_kernel(const int* __restrict__ cnt,
                                                   int* __restrict__ bsum, int n)
{
    __shared__ int red[4];
    int b = blockIdx.x, t = threadIdx.x;
    int base = b * 1024;
    int s = 0;
#pragma unroll
    for (int j = 0; j < 4; ++j) {
        int i = base + j * 256 + t;
        s += (i < n) ? cnt[i] : 0;
    }
#pragma unroll
    for (int off = 32; off; off >>= 1) s += __shfl_xor(s, off);
    if ((t & 63) == 0) red[t >> 6] = s;
    __syncthreads();
    if (t == 0) bsum[b] = red[0] + red[1] + red[2] + red[3];
}

__global__ __launch_bounds__(128) void bscan_kernel(int* __restrict__ bsum, int nb,
                                                    int* __restrict__ rowptr, int N)
{
    __shared__ int buf[128];
    int t = threadIdx.x;
    int v = (t < nb) ? bsum[t] : 0;
    buf[t] = v;
    __syncthreads();
    for (int off = 1; off < 128; off <<= 1) {
        int u = (t >= off) ? buf[t - off] : 0;
        __syncthreads();
        buf[t] += u;
        __syncthreads();
    }
    if (t < nb) bsum[t] = buf[t] - v;   // exclusive
    if (t == 127) rowptr[N] = buf[127];
}

__global__ __launch_bounds__(256) void chunkscan_kernel(const int* __restrict__ cnt,
                                                        const int* __restrict__ bsum,
                                                        int* __restrict__ rowptr, int n)
{
    __shared__ int tsum[256];
    int b = blockIdx.x, t = threadIdx.x;
    int base = b * 1024 + t * 4;
    int c[4];
    int s = 0;
#pragma unroll
    for (int j = 0; j < 4; ++j) {
        int i = base + j;
        c[j] = (i < n) ? cnt[i] : 0;
        s += c[j];
    }
    tsum[t] = s;
    __syncthreads();
    for (int off = 1; off < 256; off <<= 1) {
        int u = (t >= off) ? tsum[t - off] : 0;
        __syncthreads();
        tsum[t] += u;
        __syncthreads();
    }
    int run = bsum[b] + tsum[t] - s;
#pragma unroll
    for (int j = 0; j < 4; ++j) {
        int i = base + j;
        if (i < n) { rowptr[i] = run; run += c[j]; }
    }
}

// one block per bucket: scatter dst into csr order; cursors in LDS,
// csr_dst writes confined to this bucket's ~65KB window
__global__ __launch_bounds__(256) void pass2_scatter_kernel(const int2* __restrict__ pairs,
                                                            const int* __restrict__ bbase,
                                                            const int* __restrict__ rowptr,
                                                            int* __restrict__ csr_dst, int N)
{
    __shared__ int cur[BIN_ROWS];
    int b = blockIdx.x, t = threadIdx.x;
    int rowbase = b << BIN_SHIFT;
    int nrows = min(BIN_ROWS, N - rowbase);
    if (t < nrows) cur[t] = rowptr[rowbase + t];
    if (t + 256 < nrows) cur[t + 256] = rowptr[rowbase + t + 256];
    __syncthreads();
    int beg = bbase[b], end = bbase[b + 1];
    for (int i = beg + t; i < end; i += 256) {
        int2 p = pairs[i];
        int pos = atomicAdd(&cur[p.x - rowbase], 1);
        csr_dst[pos] = p.y;
    }
}

// ---------------------------------------------------------------------------
// Wt[n][k] = (fp16) W[k][n]
// ---------------------------------------------------------------------------
__global__ __launch_bounds__(256) void transpose16_kernel(const float* __restrict__ W,
                                                          _Float16* __restrict__ Wt,
                                                          int K, int Nw)
{
    int i = blockIdx.x * 256 + threadIdx.x;
    if (i < K * Nw) {
        int n = i / K, k = i - n * K;
        Wt[i] = (_Float16)W[(size_t)k * Nw + n];
    }
}

// ---------------------------------------------------------------------------
// MFMA f16 GEMM: C16[M,Nw] = A[M,K] @ Bt16[Nw,K]^T  (fp32 accum, fp16 out)
// CVTA: A is fp32, converted during LDS staging (layer 0 reads x directly)
// ---------------------------------------------------------------------------
#define GBM 128
#define GBN 64
#define GBK 32
#define LDP 40

template <bool CVTA>
__global__ __launch_bounds__(256) void gemm16_kernel(const void* __restrict__ Ap,
                                                     const _Float16* __restrict__ Bt,
                                                     _Float16* __restrict__ C,
                                                     int M, int Nw, int K)
{
    __shared__ __align__(16) _Float16 Ash[GBM * LDP];
    __shared__ __align__(16) _Float16 Bsh[GBN * LDP];
    const int tid = threadIdx.x;
    const int lane = tid & 63;
    const int w = tid >> 6;
    const int m0 = blockIdx.x * GBM;
    const int n0 = blockIdx.y * GBN;
    const int l15 = lane & 15;
    const int kq = lane >> 4;
    const int sr = tid >> 2;
    const int sc = tid & 3;

    f32x4 acc[2][4] = {};

    for (int k0 = 0; k0 < K; k0 += GBK) {
#pragma unroll
        for (int it = 0; it < 2; ++it) {
            int r = sr + it * 64;
            int gm = m0 + r;
            f16x8 v = {};
            if (gm < M) {
                if constexpr (CVTA) {
                    const float* Af = (const float*)Ap;
                    float4 u0 = *(const float4*)(Af + (size_t)gm * K + k0 + sc * 8);
                    float4 u1 = *(const float4*)(Af + (size_t)gm * K + k0 + sc * 8 + 4);
                    v[0] = (_Float16)u0.x; v[1] = (_Float16)u0.y;
                    v[2] = (_Float16)u0.z; v[3] = (_Float16)u0.w;
                    v[4] = (_Float16)u1.x; v[5] = (_Float16)u1.y;
                    v[6] = (_Float16)u1.z; v[7] = (_Float16)u1.w;
                } else {
                    v = *(const f16x8*)((const _Float16*)Ap + (size_t)gm * K + k0 + sc * 8);
                }
            }
            *(f16x8*)&Ash[r * LDP + sc * 8] = v;
        }
        {
            f16x8 v = *(const f16x8*)(Bt + (size_t)(n0 + sr) * K + k0 + sc * 8);
            *(f16x8*)&Bsh[sr * LDP + sc * 8] = v;
        }
        __syncthreads();

        f16x8 af[2], bf[4];
#pragma unroll
        for (int mt = 0; mt < 2; ++mt)
            af[mt] = *(const f16x8*)&Ash[(w * 32 + mt * 16 + l15) * LDP + kq * 8];
#pragma unroll
        for (int nt = 0; nt < 4; ++nt)
            bf[nt] = *(const f16x8*)&Bsh[(nt * 16 + l15) * LDP + kq * 8];
#pragma unroll
        for (int mt = 0; mt < 2; ++mt)
#pragma unroll
            for (int nt = 0; nt < 4; ++nt)
                acc[mt][nt] = __builtin_amdgcn_mfma_f32_16x16x32_f16(af[mt], bf[nt],
                                                                     acc[mt][nt], 0, 0, 0);
        __syncthreads();
    }

#pragma unroll
    for (int mt = 0; mt < 2; ++mt) {
#pragma unroll
        for (int r = 0; r < 4; ++r) {
            int gm = m0 + w * 32 + mt * 16 + kq * 4 + r;
            if (gm < M) {
#pragma unroll
                for (int nt = 0; nt < 4; ++nt)
                    C[(size_t)gm * Nw + n0 + nt * 16 + l15] = (_Float16)acc[mt][nt][r];
            }
        }
    }
}

// ---------------------------------------------------------------------------
// per-row s_src/s_dst from fp16 h (fp32 accum); one wave per row
// ---------------------------------------------------------------------------
template <int D>
__global__ __launch_bounds__(256) void s16_kernel(const _Float16* __restrict__ h,
                                                  const float* __restrict__ a,
                                                  float* __restrict__ ssrc,
                                                  float* __restrict__ sdst, int nrows)
{
    constexpr int VPT = D / 64;
    int lane = threadIdx.x & 63;
    int row = blockIdx.x * 4 + (threadIdx.x >> 6);
    if (row >= nrows) return;
    const _Float16* hp = h + (size_t)row * D + lane * VPT;
    float ps = 0.f, pd = 0.f;
    if constexpr (VPT == 4) {
        f16x4 v = *(const f16x4*)hp;
        float4 as = *(const float4*)&a[lane * 4];
        float4 ad = *(const float4*)&a[D + lane * 4];
        ps = (float)v[0] * as.x + (float)v[1] * as.y + (float)v[2] * as.z + (float)v[3] * as.w;
        pd = (float)v[0] * ad.x + (float)v[1] * ad.y + (float)v[2] * ad.z + (float)v[3] * ad.w;
    } else {
        f16x2 v = *(const f16x2*)hp;
        float2 as = *(const float2*)&a[lane * 2];
        float2 ad = *(const float2*)&a[D + lane * 2];
        ps = (float)v[0] * as.x + (float)v[1] * as.y;
        pd = (float)v[0] * ad.x + (float)v[1] * ad.y;
    }
#pragma unroll
    for (int off = 32; off; off >>= 1) {
        ps += __shfl_xor(ps, off);
        pd += __shfl_xor(pd, off);
    }
    if (lane == 0) { ssrc[row] = ps; sdst[row] = pd; }
}

// ---------------------------------------------------------------------------
// per-row edge softmax; register path for deg<=128 (mean deg = 32),
// generic 3-pass fallback otherwise
// ---------------------------------------------------------------------------
__global__ __launch_bounds__(256) void attn_kernel(const float* __restrict__ ssrc,
                                                   const float* __restrict__ sdst,
                                                   const int* __restrict__ csr_dst,
                                                   const int* __restrict__ rowptr,
                                                   float* __restrict__ attn, int nrows)
{
    int lane = threadIdx.x & 63;
    int row = blockIdx.x * 4 + (threadIdx.x >> 6);
    if (row >= nrows) return;
    int beg = rowptr[row], end = rowptr[row + 1];
    int deg = end - beg;
    if (deg == 0) return;
    float ss = ssrc[row];
    if (deg <= 128) {
        int e0 = beg + lane, e1 = beg + 64 + lane;
        float sc0 = -INFINITY, sc1 = -INFINITY;
        if (e0 < end) {
            float sc = ss + sdst[csr_dst[e0]];
            sc0 = (sc > 0.f) ? sc : LRELU_ALPHA * sc;
        }
        if (e1 < end) {
            float sc = ss + sdst[csr_dst[e1]];
            sc1 = (sc > 0.f) ? sc : LRELU_ALPHA * sc;
        }
        float m = fmaxf(sc0, sc1);
#pragma unroll
        for (int off = 32; off; off >>= 1) m = fmaxf(m, __shfl_xor(m, off));
        float ex0 = (e0 < end) ? expf(sc0 - m) : 0.f;
        float ex1 = (e1 < end) ? expf(sc1 - m) : 0.f;
        float z = ex0 + ex1;
#pragma unroll
        for (int off = 32; off; off >>= 1) z += __shfl_xor(z, off);
        float rz = 1.f / z;
        if (e0 < end) attn[e0] = ex0 * rz;
        if (e1 < end) attn[e1] = ex1 * rz;
    } else {
        float m = -INFINITY;
        for (int e = beg + lane; e < end; e += 64) {
            float sc = ss + sdst[csr_dst[e]];
            sc = (sc > 0.f) ? sc : LRELU_ALPHA * sc;
            attn[e] = sc;
            m = fmaxf(m, sc);
        }
#pragma unroll
        for (int off = 32; off; off >>= 1) m = fmaxf(m, __shfl_xor(m, off));
        float z = 0.f;
        for (int e = beg + lane; e < end; e += 64) {
            float ex = expf(attn[e] - m);
            attn[e] = ex;
            z += ex;
        }
#pragma unroll
        for (int off = 32; off; off >>= 1) z += __shfl_xor(z, off);
        float rz = 1.f / z;
        for (int e = beg + lane; e < end; e += 64) attn[e] *= rz;
    }
}

// ---------------------------------------------------------------------------
// aggregation: one wave per row, 16 lanes per edge, 4 edges in flight
// ---------------------------------------------------------------------------
__device__ __forceinline__ float eluf(float x) { return x > 0.f ? x : expm1f(x); }

template <int D>
__global__ __launch_bounds__(256) void aggregate16_kernel(const _Float16* __restrict__ h,
                                                          const float* __restrict__ attn,
                                                          const int* __restrict__ csr_dst,
                                                          const int* __restrict__ rowptr,
                                                          _Float16* __restrict__ out, int nrows)
{
    constexpr int HPL = D / 16;            // halves per lane: 16 (D=256) or 8 (D=128)
    int lane = threadIdx.x & 63;
    int row = blockIdx.x * 4 + (threadIdx.x >> 6);
    if (row >= nrows) return;
    int beg = rowptr[row], end = rowptr[row + 1];
    int sub = lane >> 4;
    int cl = lane & 15;
    float acc[HPL] = {};
    for (int e = beg + sub; e < end; e += 4) {
        float a = attn[e];
        int d = csr_dst[e];
        const _Float16* hp = h + (size_t)d * D + cl * HPL;
        if constexpr (HPL == 16) {
            f16x8 v0 = *(const f16x8*)hp;
            f16x8 v1 = *(const f16x8*)(hp + 8);
#pragma unroll
            for (int j = 0; j < 8; ++j) acc[j] += a * (float)v0[j];
#pragma unroll
            for (int j = 0; j < 8; ++j) acc[8 + j] += a * (float)v1[j];
        } else {
            f16x8 v = *(const f16x8*)hp;
#pragma unroll
            for (int j = 0; j < 8; ++j) acc[j] += a * (float)v[j];
        }
    }
#pragma unroll
    for (int j = 0; j < HPL; ++j) {
        acc[j] += __shfl_xor(acc[j], 16);
        acc[j] += __shfl_xor(acc[j], 32);
    }
    if (sub == 0) {
        _Float16* op = out + (size_t)row * D + cl * HPL;
        if constexpr (HPL == 16) {
            f16x8 o0, o1;
#pragma unroll
            for (int j = 0; j < 8; ++j) o0[j] = (_Float16)eluf(acc[j]);
#pragma unroll
            for (int j = 0; j < 8; ++j) o1[j] = (_Float16)eluf(acc[8 + j]);
            *(f16x8*)op = o0;
            *(f16x8*)(op + 8) = o1;
        } else {
            f16x8 o;
#pragma unroll
            for (int j = 0; j < 8; ++j) o[j] = (_Float16)eluf(acc[j]);
            *(f16x8*)op = o;
        }
    }
}

// ---------------------------------------------------------------------------
// final: logits = h1 @ lin_w + lin_b ; log_softmax; one wave per row
// ---------------------------------------------------------------------------
__global__ __launch_bounds__(256) void final16_kernel(const _Float16* __restrict__ h, // [N,128]
                                                      const float* __restrict__ lw,   // [128,40]
                                                      const float* __restrict__ lb,   // [40]
                                                      float* __restrict__ out, int nrows)
{
    __shared__ __align__(16) float rowbuf[4][128];
    int lane = threadIdx.x & 63;
    int wv = threadIdx.x >> 6;
    int row = blockIdx.x * 4 + wv;
    bool active = row < nrows;
    if (active) {
        f16x2 v = *(const f16x2*)&h[(size_t)row * 128 + lane * 2];
        rowbuf[wv][lane * 2] = (float)v[0];
        rowbuf[wv][lane * 2 + 1] = (float)v[1];
    }
    __syncthreads();
    float logit = 0.f;
    if (active && lane < 40) {
        float s = lb[lane];
        for (int k = 0; k < 128; ++k) s += rowbuf[wv][k] * lw[k * 40 + lane];
        logit = s;
    }
    float v = (active && lane < 40) ? logit : -INFINITY;
#pragma unroll
    for (int off = 32; off; off >>= 1) v = fmaxf(v, __shfl_xor(v, off));
    float ex = (active && lane < 40) ? expf(logit - v) : 0.f;
    float zs = ex;
#pragma unroll
    for (int off = 32; off; off >>= 1) zs += __shfl_xor(zs, off);
    if (active && lane < 40) out[(size_t)row * 40 + lane] = logit - v - logf(zs);
}

// ---------------------------------------------------------------------------
extern "C" void kernel_launch(void* const* d_in, const int* in_sizes, int n_in,
                              void* d_out, int out_size, void* d_ws, size_t ws_size,
                              hipStream_t stream)
{
    const float* x   = (const float*)d_in[0];   // [N,256]
    const int*  edge = (const int*)d_in[1];     // [2,E]
    const float* W0  = (const float*)d_in[2];   // [256,256]
    const float* a0  = (const float*)d_in[3];   // [512,1]
    const float* W1  = (const float*)d_in[4];   // [256,128]
    const float* a1  = (const float*)d_in[5];   // [256,1]
    const float* lw  = (const float*)d_in[6];   // [128,40]
    const float* lb  = (const float*)d_in[7];   // [40]
    float* out = (float*)d_out;

    const int N = in_sizes[0] / 256;
    const int E = in_sizes[1] / 2;
    const int* src = edge;
    const int* dst = edge + E;

    // ---- workspace layout ----
    _Float16* bufA = (_Float16*)d_ws;                 // N*256 halves (h0, then h1)
    _Float16* bufB = bufA + (size_t)N * 256;          // N*256 halves (h0', then h1')
    _Float16* W0t  = bufB + (size_t)N * 256;          // 256*256
    _Float16* W1t  = W0t + 256 * 256;                 // 128*256
    float* ssrc = (float*)(W1t + 128 * 256);          // N
    float* sdst = ssrc + N;                            // N
    float* attn = sdst + N;                            // E
    int* rowptr  = (int*)(attn + E);                   // N+1
    int* cnt     = rowptr + (N + 1);                   // N
    int* csr_dst = cnt + N;                            // E
    int* bsum    = csr_dst + E;                        // 128
    int* bhist   = bsum + 128;                         // 256
    int* bbase   = bhist + 256;                        // 257
    int* gcur    = bbase + 257;                        // 256
    // pairs aliases bufA: only live before gemm-0 writes bufA (stream-ordered)
    int2* pairs  = (int2*)bufA;                        // E int2

    const int rowBlocks = (N + 3) / 4;
    const int nb = (N + 1023) / 1024;                  // scan chunks (<=128)
    const int NB = (N + BIN_ROWS - 1) >> BIN_SHIFT;    // buckets (<=256)
    const int blocksE = (E + 4095) / 4096;

    // ---- CSR build (bucketed) ----
    hipMemsetAsync(bhist, 0, 256 * sizeof(int), stream);
    bucket_count_kernel<<<blocksE, 256, 0, stream>>>(src, bhist, E);
    bucket_scan_kernel<<<1, 256, 0, stream>>>(bhist, bbase, gcur, E);
    pass1_bin_kernel<<<blocksE, 256, 0, stream>>>(src, dst, gcur, pairs, E);
    row_count_kernel<<<NB, 256, 0, stream>>>(pairs, bbase, cnt, N);
    bsum_kernel<<<nb, 256, 0, stream>>>(cnt, bsum, N);
    bscan_kernel<<<1, 128, 0, stream>>>(bsum, nb, rowptr, N);
    chunkscan_kernel<<<nb, 256, 0, stream>>>(cnt, bsum, rowptr, N);
    pass2_scatter_kernel<<<NB, 256, 0, stream>>>(pairs, bbase, rowptr, csr_dst, N);

    // ---- weight transposes (fp16) ----
    transpose16_kernel<<<(256 * 256 + 255) / 256, 256, 0, stream>>>(W0, W0t, 256, 256);
    transpose16_kernel<<<(128 * 256 + 255) / 256, 256, 0, stream>>>(W1, W1t, 256, 128);

    // ---- layer 0: d = 256 (A = x fp32, converted in staging) ----
    gemm16_kernel<true><<<dim3((N + GBM - 1) / GBM, 256 / GBN), 256, 0, stream>>>(x, W0t, bufA, N, 256, 256);
    s16_kernel<256><<<rowBlocks, 256, 0, stream>>>(bufA, a0, ssrc, sdst, N);
    attn_kernel<<<rowBlocks, 256, 0, stream>>>(ssrc, sdst, csr_dst, rowptr, attn, N);
    aggregate16_kernel<256><<<rowBlocks, 256, 0, stream>>>(bufA, attn, csr_dst, rowptr, bufB, N);

    // ---- layer 1: d = 128 ----
    gemm16_kernel<false><<<dim3((N + GBM - 1) / GBM, 128 / GBN), 256, 0, stream>>>(bufB, W1t, bufA, N, 128, 256);
    s16_kernel<128><<<rowBlocks, 256, 0, stream>>>(bufA, a1, ssrc, sdst, N);
    attn_kernel<<<rowBlocks, 256, 0, stream>>>(ssrc, sdst, csr_dst, rowptr, attn, N);
    aggregate16_kernel<128><<<rowBlocks, 256, 0, stream>>>(bufA, attn, csr_dst, rowptr, bufB, N);

    // ---- final linear + log_softmax ----
    final16_kernel<<<rowBlocks, 256, 0, stream>>>(bufB, lw, lb, out, N);
}

// Round 4
// 693.026 us; speedup vs baseline: 2.8155x; 1.0871x over previous
//
#include <hip/hip_runtime.h>
#include <cstddef>
#include <cstdint>

#define LRELU_ALPHA 0.2f
#define BIN_SHIFT 9
#define BIN_ROWS  (1 << BIN_SHIFT)   // 512 rows per bucket
// packed pair: (local_row << 17) | dst  -- requires N <= 131072 (N = 100000)
#define DST_BITS 17
#define DST_MASK ((1 << DST_BITS) - 1)

typedef _Float16 f16x8 __attribute__((ext_vector_type(8)));
typedef _Float16 f16x4 __attribute__((ext_vector_type(4)));
typedef _Float16 f16x2 __attribute__((ext_vector_type(2)));
typedef float    f32x4 __attribute__((ext_vector_type(4)));

// ---------------------------------------------------------------------------
// CSR build, locality-bucketed, packed pairs
// ---------------------------------------------------------------------------
__global__ __launch_bounds__(256) void bucket_count_kernel(const int* __restrict__ src,
                                                           int* __restrict__ bhist, int E)
{
    __shared__ int hist[256];
    int t = threadIdx.x;
    hist[t] = 0;
    __syncthreads();
    int base = blockIdx.x * 4096;
#pragma unroll
    for (int j = 0; j < 16; ++j) {
        int i = base + j * 256 + t;
        if (i < E) atomicAdd(&hist[src[i] >> BIN_SHIFT], 1);
    }
    __syncthreads();
    if (hist[t]) atomicAdd(&bhist[t], hist[t]);
}

__global__ __launch_bounds__(256) void bucket_scan_kernel(const int* __restrict__ bhist,
                                                          int* __restrict__ bbase,
                                                          int* __restrict__ gcur, int E)
{
    __shared__ int buf[256];
    int t = threadIdx.x;
    int v = bhist[t];
    buf[t] = v;
    __syncthreads();
    for (int off = 1; off < 256; off <<= 1) {
        int u = (t >= off) ? buf[t - off] : 0;
        __syncthreads();
        buf[t] += u;
        __syncthreads();
    }
    int excl = buf[t] - v;
    bbase[t] = excl;
    gcur[t] = excl;
    if (t == 255) bbase[256] = buf[255];
}

// bin packed (lrow|dst) into bucket-contiguous order
__global__ __launch_bounds__(256) void pass1_bin_kernel(const int* __restrict__ src,
                                                        const int* __restrict__ dst,
                                                        int* __restrict__ gcur,
                                                        int* __restrict__ pairs, int E)
{
    __shared__ int hist[256];
    __shared__ int cur[256];
    int t = threadIdx.x;
    hist[t] = 0;
    __syncthreads();
    int base = blockIdx.x * 4096;
    int s_[16], d_[16];
#pragma unroll
    for (int j = 0; j < 16; ++j) {
        int i = base + j * 256 + t;
        if (i < E) {
            s_[j] = src[i];
            d_[j] = dst[i];
            atomicAdd(&hist[s_[j] >> BIN_SHIFT], 1);
        } else s_[j] = -1;
    }
    __syncthreads();
    cur[t] = atomicAdd(&gcur[t], hist[t]);
    __syncthreads();
#pragma unroll
    for (int j = 0; j < 16; ++j) {
        if (s_[j] >= 0) {
            int pos = atomicAdd(&cur[s_[j] >> BIN_SHIFT], 1);
            pairs[pos] = ((s_[j] & (BIN_ROWS - 1)) << DST_BITS) | d_[j];
        }
    }
}

__global__ __launch_bounds__(256) void row_count_kernel(const int* __restrict__ pairs,
                                                        const int* __restrict__ bbase,
                                                        int* __restrict__ cnt, int N)
{
    __shared__ int c[BIN_ROWS];
    int b = blockIdx.x, t = threadIdx.x;
    int rowbase = b << BIN_SHIFT;
    int nrows = min(BIN_ROWS, N - rowbase);
    c[t] = 0; c[t + 256] = 0;
    __syncthreads();
    int beg = bbase[b], end = bbase[b + 1];
    for (int i = beg + t; i < end; i += 256)
        atomicAdd(&c[pairs[i] >> DST_BITS], 1);
    __syncthreads();
    if (t < nrows) cnt[rowbase + t] = c[t];
    if (t + 256 < nrows) cnt[rowbase + t + 256] = c[t + 256];
}

__global__ __launch_bounds__(256) void bsum_kernel(const int* __restrict__ cnt,
                                                   int* __restrict__ bsum, int n)
{
    __shared__ int red[4];
    int b = blockIdx.x, t = threadIdx.x;
    int base = b * 1024;
    int s = 0;
#pragma unroll
    for (int j = 0; j < 4; ++j) {
        int i = base + j * 256 + t;
        s += (i < n) ? cnt[i] : 0;
    }
#pragma unroll
    for (int off = 32; off; off >>= 1) s += __shfl_xor(s, off);
    if ((t & 63) == 0) red[t >> 6] = s;
    __syncthreads();
    if (t == 0) bsum[b] = red[0] + red[1] + red[2] + red[3];
}

__global__ __launch_bounds__(128) void bscan_kernel(int* __restrict__ bsum, int nb,
                                                    int* __restrict__ rowptr, int N)
{
    __shared__ int buf[128];
    int t = threadIdx.x;
    int v = (t < nb) ? bsum[t] : 0;
    buf[t] = v;
    __syncthreads();
    for (int off = 1; off < 128; off <<= 1) {
        int u = (t >= off) ? buf[t - off] : 0;
        __syncthreads();
        buf[t] += u;
        __syncthreads();
    }
    if (t < nb) bsum[t] = buf[t] - v;   // exclusive
    if (t == 127) rowptr[N] = buf[127];
}

__global__ __launch_bounds__(256) void chunkscan_kernel(const int* __restrict__ cnt,
                                                        const int* __restrict__ bsum,
                                                        int* __restrict__ rowptr, int n)
{
    __shared__ int tsum[256];
    int b = blockIdx.x, t = threadIdx.x;
    int base = b * 1024 + t * 4;
    int c[4];
    int s = 0;
#pragma unroll
    for (int j = 0; j < 4; ++j) {
        int i = base + j;
        c[j] = (i < n) ? cnt[i] : 0;
        s += c[j];
    }
    tsum[t] = s;
    __syncthreads();
    for (int off = 1; off < 256; off <<= 1) {
        int u = (t >= off) ? tsum[t - off] : 0;
        __syncthreads();
        tsum[t] += u;
        __syncthreads();
    }
    int run = bsum[b] + tsum[t] - s;
#pragma unroll
    for (int j = 0; j < 4; ++j) {
        int i = base + j;
        if (i < n) { rowptr[i] = run; run += c[j]; }
    }
}

__global__ __launch_bounds__(256) void pass2_scatter_kernel(const int* __restrict__ pairs,
                                                            const int* __restrict__ bbase,
                                                            const int* __restrict__ rowptr,
                                                            int* __restrict__ csr_dst, int N)
{
    __shared__ int cur[BIN_ROWS];
    int b = blockIdx.x, t = threadIdx.x;
    int rowbase = b << BIN_SHIFT;
    int nrows = min(BIN_ROWS, N - rowbase);
    if (t < nrows) cur[t] = rowptr[rowbase + t];
    if (t + 256 < nrows) cur[t + 256] = rowptr[rowbase + t + 256];
    __syncthreads();
    int beg = bbase[b], end = bbase[b + 1];
    for (int i = beg + t; i < end; i += 256) {
        int p = pairs[i];
        int pos = atomicAdd(&cur[p >> DST_BITS], 1);
        csr_dst[pos] = p & DST_MASK;
    }
}

// ---------------------------------------------------------------------------
// Wt[n][k] = (fp16) W[k][n]
// ---------------------------------------------------------------------------
__global__ __launch_bounds__(256) void transpose16_kernel(const float* __restrict__ W,
                                                          _Float16* __restrict__ Wt,
                                                          int K, int Nw)
{
    int i = blockIdx.x * 256 + threadIdx.x;
    if (i < K * Nw) {
        int n = i / K, k = i - n * K;
        Wt[i] = (_Float16)W[(size_t)k * Nw + n];
    }
}

// ---------------------------------------------------------------------------
// MFMA f16 GEMM: C16[M,Nw] = A[M,K] @ Bt16[Nw,K]^T  (fp32 accum, fp16 out)
// ---------------------------------------------------------------------------
#define GBM 128
#define GBN 64
#define GBK 32
#define LDP 40

template <bool CVTA>
__global__ __launch_bounds__(256) void gemm16_kernel(const void* __restrict__ Ap,
                                                     const _Float16* __restrict__ Bt,
                                                     _Float16* __restrict__ C,
                                                     int M, int Nw, int K)
{
    __shared__ __align__(16) _Float16 Ash[GBM * LDP];
    __shared__ __align__(16) _Float16 Bsh[GBN * LDP];
    const int tid = threadIdx.x;
    const int lane = tid & 63;
    const int w = tid >> 6;
    const int m0 = blockIdx.x * GBM;
    const int n0 = blockIdx.y * GBN;
    const int l15 = lane & 15;
    const int kq = lane >> 4;
    const int sr = tid >> 2;
    const int sc = tid & 3;

    f32x4 acc[2][4] = {};

    for (int k0 = 0; k0 < K; k0 += GBK) {
#pragma unroll
        for (int it = 0; it < 2; ++it) {
            int r = sr + it * 64;
            int gm = m0 + r;
            f16x8 v = {};
            if (gm < M) {
                if constexpr (CVTA) {
                    const float* Af = (const float*)Ap;
                    float4 u0 = *(const float4*)(Af + (size_t)gm * K + k0 + sc * 8);
                    float4 u1 = *(const float4*)(Af + (size_t)gm * K + k0 + sc * 8 + 4);
                    v[0] = (_Float16)u0.x; v[1] = (_Float16)u0.y;
                    v[2] = (_Float16)u0.z; v[3] = (_Float16)u0.w;
                    v[4] = (_Float16)u1.x; v[5] = (_Float16)u1.y;
                    v[6] = (_Float16)u1.z; v[7] = (_Float16)u1.w;
                } else {
                    v = *(const f16x8*)((const _Float16*)Ap + (size_t)gm * K + k0 + sc * 8);
                }
            }
            *(f16x8*)&Ash[r * LDP + sc * 8] = v;
        }
        {
            f16x8 v = *(const f16x8*)(Bt + (size_t)(n0 + sr) * K + k0 + sc * 8);
            *(f16x8*)&Bsh[sr * LDP + sc * 8] = v;
        }
        __syncthreads();

        f16x8 af[2], bf[4];
#pragma unroll
        for (int mt = 0; mt < 2; ++mt)
            af[mt] = *(const f16x8*)&Ash[(w * 32 + mt * 16 + l15) * LDP + kq * 8];
#pragma unroll
        for (int nt = 0; nt < 4; ++nt)
            bf[nt] = *(const f16x8*)&Bsh[(nt * 16 + l15) * LDP + kq * 8];
#pragma unroll
        for (int mt = 0; mt < 2; ++mt)
#pragma unroll
            for (int nt = 0; nt < 4; ++nt)
                acc[mt][nt] = __builtin_amdgcn_mfma_f32_16x16x32_f16(af[mt], bf[nt],
                                                                     acc[mt][nt], 0, 0, 0);
        __syncthreads();
    }

#pragma unroll
    for (int mt = 0; mt < 2; ++mt) {
#pragma unroll
        for (int r = 0; r < 4; ++r) {
            int gm = m0 + w * 32 + mt * 16 + kq * 4 + r;
            if (gm < M) {
#pragma unroll
                for (int nt = 0; nt < 4; ++nt)
                    C[(size_t)gm * Nw + n0 + nt * 16 + l15] = (_Float16)acc[mt][nt][r];
            }
        }
    }
}

// ---------------------------------------------------------------------------
// per-row s_src/s_dst from fp16 h (fp32 accum); one wave per row
// ---------------------------------------------------------------------------
template <int D>
__global__ __launch_bounds__(256) void s16_kernel(const _Float16* __restrict__ h,
                                                  const float* __restrict__ a,
                                                  float* __restrict__ ssrc,
                                                  float* __restrict__ sdst, int nrows)
{
    constexpr int VPT = D / 64;
    int lane = threadIdx.x & 63;
    int row = blockIdx.x * 4 + (threadIdx.x >> 6);
    if (row >= nrows) return;
    const _Float16* hp = h + (size_t)row * D + lane * VPT;
    float ps = 0.f, pd = 0.f;
    if constexpr (VPT == 4) {
        f16x4 v = *(const f16x4*)hp;
        float4 as = *(const float4*)&a[lane * 4];
        float4 ad = *(const float4*)&a[D + lane * 4];
        ps = (float)v[0] * as.x + (float)v[1] * as.y + (float)v[2] * as.z + (float)v[3] * as.w;
        pd = (float)v[0] * ad.x + (float)v[1] * ad.y + (float)v[2] * ad.z + (float)v[3] * ad.w;
    } else {
        f16x2 v = *(const f16x2*)hp;
        float2 as = *(const float2*)&a[lane * 2];
        float2 ad = *(const float2*)&a[D + lane * 2];
        ps = (float)v[0] * as.x + (float)v[1] * as.y;
        pd = (float)v[0] * ad.x + (float)v[1] * ad.y;
    }
#pragma unroll
    for (int off = 32; off; off >>= 1) {
        ps += __shfl_xor(ps, off);
        pd += __shfl_xor(pd, off);
    }
    if (lane == 0) { ssrc[row] = ps; sdst[row] = pd; }
}

// ---------------------------------------------------------------------------
// FUSED per-row softmax + aggregation + ELU.
// One wave per row. deg<=128: weights+dst stashed in per-wave LDS (no global
// attn round-trip). deg>128: 3-pass spill fallback.
// Aggregation: 16 lanes/edge, 4 edges in flight, 1-deep software pipeline.
// ---------------------------------------------------------------------------
__device__ __forceinline__ float eluf(float x) { return x > 0.f ? x : expm1f(x); }

template <int D>
__global__ __launch_bounds__(256) void attnagg_kernel(const _Float16* __restrict__ h,
                                                      const float* __restrict__ ssrc,
                                                      const float* __restrict__ sdst,
                                                      const int* __restrict__ csr_dst,
                                                      const int* __restrict__ rowptr,
                                                      float* __restrict__ attn_spill,
                                                      _Float16* __restrict__ out, int nrows)
{
    constexpr int HPL = D / 16;            // halves per lane: 16 (D=256) or 8 (D=128)
    __shared__ float wbuf[4][128];
    __shared__ int   dbuf[4][128];
    int lane = threadIdx.x & 63;
    int wv = threadIdx.x >> 6;
    int row = blockIdx.x * 4 + wv;
    if (row >= nrows) return;
    int beg = rowptr[row], end = rowptr[row + 1];
    int deg = end - beg;
    bool small = (deg <= 128);

    if (deg > 0) {
        float ss = ssrc[row];
        if (small) {
            int e0 = beg + lane, e1 = e0 + 64;
            int d0 = 0, d1 = 0;
            float sc0 = -INFINITY, sc1 = -INFINITY;
            if (e0 < end) {
                d0 = csr_dst[e0];
                float sc = ss + sdst[d0];
                sc0 = (sc > 0.f) ? sc : LRELU_ALPHA * sc;
            }
            if (e1 < end) {
                d1 = csr_dst[e1];
                float sc = ss + sdst[d1];
                sc1 = (sc > 0.f) ? sc : LRELU_ALPHA * sc;
            }
            float m = fmaxf(sc0, sc1);
#pragma unroll
            for (int off = 32; off; off >>= 1) m = fmaxf(m, __shfl_xor(m, off));
            float ex0 = (e0 < end) ? expf(sc0 - m) : 0.f;
            float ex1 = (e1 < end) ? expf(sc1 - m) : 0.f;
            float z = ex0 + ex1;
#pragma unroll
            for (int off = 32; off; off >>= 1) z += __shfl_xor(z, off);
            float rz = 1.f / z;
            if (e0 < end) { wbuf[wv][lane] = ex0 * rz; dbuf[wv][lane] = d0; }
            if (e1 < end) { wbuf[wv][64 + lane] = ex1 * rz; dbuf[wv][64 + lane] = d1; }
        } else {
            float m = -INFINITY;
            for (int e = beg + lane; e < end; e += 64) {
                float sc = ss + sdst[csr_dst[e]];
                sc = (sc > 0.f) ? sc : LRELU_ALPHA * sc;
                attn_spill[e] = sc;
                m = fmaxf(m, sc);
            }
#pragma unroll
            for (int off = 32; off; off >>= 1) m = fmaxf(m, __shfl_xor(m, off));
            float z = 0.f;
            for (int e = beg + lane; e < end; e += 64) {
                float ex = expf(attn_spill[e] - m);
                attn_spill[e] = ex;
                z += ex;
            }
#pragma unroll
            for (int off = 32; off; off >>= 1) z += __shfl_xor(z, off);
            float rz = 1.f / z;
            for (int e = beg + lane; e < end; e += 64) attn_spill[e] *= rz;
        }
    }

    // ---- aggregation ----
    int sub = lane >> 4;
    int cl = lane & 15;
    float acc[HPL] = {};

    if (small) {
        int k = sub;
        bool has = k < deg;
        float a_c = 0.f;
        f16x8 v0_c = {}, v1_c = {};
        if (has) {
            a_c = wbuf[wv][k];
            int d = dbuf[wv][k];
            const _Float16* hp = h + (size_t)d * D + cl * HPL;
            v0_c = *(const f16x8*)hp;
            if constexpr (HPL == 16) v1_c = *(const f16x8*)(hp + 8);
        }
        while (has) {
            int kn = k + 4;
            bool hn = kn < deg;
            float a_n = 0.f;
            f16x8 v0_n = {}, v1_n = {};
            if (hn) {
                a_n = wbuf[wv][kn];
                int d = dbuf[wv][kn];
                const _Float16* hp = h + (size_t)d * D + cl * HPL;
                v0_n = *(const f16x8*)hp;
                if constexpr (HPL == 16) v1_n = *(const f16x8*)(hp + 8);
            }
#pragma unroll
            for (int j = 0; j < 8; ++j) acc[j] += a_c * (float)v0_c[j];
            if constexpr (HPL == 16) {
#pragma unroll
                for (int j = 0; j < 8; ++j) acc[8 + j] += a_c * (float)v1_c[j];
            }
            a_c = a_n; v0_c = v0_n; v1_c = v1_n;
            k = kn; has = hn;
        }
    } else {
        for (int e = beg + sub; e < end; e += 4) {
            float a = attn_spill[e];
            int d = csr_dst[e];
            const _Float16* hp = h + (size_t)d * D + cl * HPL;
            if constexpr (HPL == 16) {
                f16x8 v0 = *(const f16x8*)hp;
                f16x8 v1 = *(const f16x8*)(hp + 8);
#pragma unroll
                for (int j = 0; j < 8; ++j) acc[j] += a * (float)v0[j];
#pragma unroll
                for (int j = 0; j < 8; ++j) acc[8 + j] += a * (float)v1[j];
            } else {
                f16x8 v = *(const f16x8*)hp;
#pragma unroll
                for (int j = 0; j < 8; ++j) acc[j] += a * (float)v[j];
            }
        }
    }

#pragma unroll
    for (int j = 0; j < HPL; ++j) {
        acc[j] += __shfl_xor(acc[j], 16);
        acc[j] += __shfl_xor(acc[j], 32);
    }
    if (sub == 0) {
        _Float16* op = out + (size_t)row * D + cl * HPL;
        if constexpr (HPL == 16) {
            f16x8 o0, o1;
#pragma unroll
            for (int j = 0; j < 8; ++j) o0[j] = (_Float16)eluf(acc[j]);
#pragma unroll
            for (int j = 0; j < 8; ++j) o1[j] = (_Float16)eluf(acc[8 + j]);
            *(f16x8*)op = o0;
            *(f16x8*)(op + 8) = o1;
        } else {
            f16x8 o;
#pragma unroll
            for (int j = 0; j < 8; ++j) o[j] = (_Float16)eluf(acc[j]);
            *(f16x8*)op = o;
        }
    }
}

// ---------------------------------------------------------------------------
// final: logits = h1 @ lin_w + lin_b ; log_softmax; one wave per row
// ---------------------------------------------------------------------------
__global__ __launch_bounds__(256) void final16_kernel(const _Float16* __restrict__ h, // [N,128]
                                                      const float* __restrict__ lw,   // [128,40]
                                                      const float* __restrict__ lb,   // [40]
                                                      float* __restrict__ out, int nrows)
{
    __shared__ __align__(16) float rowbuf[4][128];
    int lane = threadIdx.x & 63;
    int wv = threadIdx.x >> 6;
    int row = blockIdx.x * 4 + wv;
    bool active = row < nrows;
    if (active) {
        f16x2 v = *(const f16x2*)&h[(size_t)row * 128 + lane * 2];
        rowbuf[wv][lane * 2] = (float)v[0];
        rowbuf[wv][lane * 2 + 1] = (float)v[1];
    }
    __syncthreads();
    float logit = 0.f;
    if (active && lane < 40) {
        float s = lb[lane];
        for (int k = 0; k < 128; ++k) s += rowbuf[wv][k] * lw[k * 40 + lane];
        logit = s;
    }
    float v = (active && lane < 40) ? logit : -INFINITY;
#pragma unroll
    for (int off = 32; off; off >>= 1) v = fmaxf(v, __shfl_xor(v, off));
    float ex = (active && lane < 40) ? expf(logit - v) : 0.f;
    float zs = ex;
#pragma unroll
    for (int off = 32; off; off >>= 1) zs += __shfl_xor(zs, off);
    if (active && lane < 40) out[(size_t)row * 40 + lane] = logit - v - logf(zs);
}

// ---------------------------------------------------------------------------
extern "C" void kernel_launch(void* const* d_in, const int* in_sizes, int n_in,
                              void* d_out, int out_size, void* d_ws, size_t ws_size,
                              hipStream_t stream)
{
    const float* x   = (const float*)d_in[0];   // [N,256]
    const int*  edge = (const int*)d_in[1];     // [2,E]
    const float* W0  = (const float*)d_in[2];   // [256,256]
    const float* a0  = (const float*)d_in[3];   // [512,1]
    const float* W1  = (const float*)d_in[4];   // [256,128]
    const float* a1  = (const float*)d_in[5];   // [256,1]
    const float* lw  = (const float*)d_in[6];   // [128,40]
    const float* lb  = (const float*)d_in[7];   // [40]
    float* out = (float*)d_out;

    const int N = in_sizes[0] / 256;
    const int E = in_sizes[1] / 2;
    const int* src = edge;
    const int* dst = edge + E;

    // ---- workspace layout ----
    _Float16* bufA = (_Float16*)d_ws;                 // N*256 halves (h0, then h1)
    _Float16* bufB = bufA + (size_t)N * 256;          // N*256 halves (h0', then h1')
    _Float16* W0t  = bufB + (size_t)N * 256;          // 256*256
    _Float16* W1t  = W0t + 256 * 256;                 // 128*256
    float* ssrc = (float*)(W1t + 128 * 256);          // N
    float* sdst = ssrc + N;                            // N
    float* attn = sdst + N;                            // E (spill for deg>128 rows)
    int* rowptr  = (int*)(attn + E);                   // N+1
    int* cnt     = rowptr + (N + 1);                   // N
    int* csr_dst = cnt + N;                            // E
    int* bsum    = csr_dst + E;                        // 128
    int* bhist   = bsum + 128;                         // 256
    int* bbase   = bhist + 256;                        // 257
    int* gcur    = bbase + 257;                        // 256
    // pairs aliases bufA: only live before gemm-0 writes bufA (stream-ordered)
    int* pairs   = (int*)bufA;                         // E ints (packed lrow|dst)

    const int rowBlocks = (N + 3) / 4;
    const int nb = (N + 1023) / 1024;                  // scan chunks (<=128)
    const int NB = (N + BIN_ROWS - 1) >> BIN_SHIFT;    // buckets (<=256)
    const int blocksE = (E + 4095) / 4096;

    // ---- CSR build (bucketed, packed) ----
    hipMemsetAsync(bhist, 0, 256 * sizeof(int), stream);
    bucket_count_kernel<<<blocksE, 256, 0, stream>>>(src, bhist, E);
    bucket_scan_kernel<<<1, 256, 0, stream>>>(bhist, bbase, gcur, E);
    pass1_bin_kernel<<<blocksE, 256, 0, stream>>>(src, dst, gcur, pairs, E);
    row_count_kernel<<<NB, 256, 0, stream>>>(pairs, bbase, cnt, N);
    bsum_kernel<<<nb, 256, 0, stream>>>(cnt, bsum, N);
    bscan_kernel<<<1, 128, 0, stream>>>(bsum, nb, rowptr, N);
    chunkscan_kernel<<<nb, 256, 0, stream>>>(cnt, bsum, rowptr, N);
    pass2_scatter_kernel<<<NB, 256, 0, stream>>>(pairs, bbase, rowptr, csr_dst, N);

    // ---- weight transposes (fp16) ----
    transpose16_kernel<<<(256 * 256 + 255) / 256, 256, 0, stream>>>(W0, W0t, 256, 256);
    transpose16_kernel<<<(128 * 256 + 255) / 256, 256, 0, stream>>>(W1, W1t, 256, 128);

    // ---- layer 0: d = 256 (A = x fp32, converted in staging) ----
    gemm16_kernel<true><<<dim3((N + GBM - 1) / GBM, 256 / GBN), 256, 0, stream>>>(x, W0t, bufA, N, 256, 256);
    s16_kernel<256><<<rowBlocks, 256, 0, stream>>>(bufA, a0, ssrc, sdst, N);
    attnagg_kernel<256><<<rowBlocks, 256, 0, stream>>>(bufA, ssrc, sdst, csr_dst, rowptr, attn, bufB, N);

    // ---- layer 1: d = 128 ----
    gemm16_kernel<false><<<dim3((N + GBM - 1) / GBM, 128 / GBN), 256, 0, stream>>>(bufB, W1t, bufA, N, 128, 256);
    s16_kernel<128><<<rowBlocks, 256, 0, stream>>>(bufA, a1, ssrc, sdst, N);
    attnagg_kernel<128><<<rowBlocks, 256, 0, stream>>>(bufA, ssrc, sdst, csr_dst, rowptr, attn, bufB, N);

    // ---- final linear + log_softmax ----
    final16_kernel<<<rowBlocks, 256, 0, stream>>>(bufB, lw, lb, out, N);
}